// Round 7
// baseline (639.823 us; speedup 1.0000x reference)
//
#include <hip/hip_runtime.h>

namespace {

constexpr int TT = 512;   // timesteps
constexpr int H  = 64;    // hidden units per layer
constexpr int NB = 8;     // batches per block; MFMA cols 8..15 carry h_lo corrections
constexpr int NT = 256;   // 4 waves, 1/SIMD; each wave does BOTH layers for its tile-set
constexpr float L2E = 1.442695041f;

typedef float  f32x4  __attribute__((ext_vector_type(4)));
typedef short  bf16x8 __attribute__((ext_vector_type(8)));

#define MFMA(A, B, C) (C) = __builtin_amdgcn_mfma_f32_16x16x32_bf16((A), (B), (C), 0, 0, 0)

__device__ __forceinline__ float exp2_hw(float x) {
    float r; asm("v_exp_f32 %0, %1" : "=v"(r) : "v"(x)); return r;
}
__device__ __forceinline__ float sigm_pre(float zs) {     // zs = -log2e * z
    return __builtin_amdgcn_rcpf(1.0f + exp2_hw(zs));
}
__device__ __forceinline__ float tanh_pre(float zs) {     // zs = -2*log2e * z
    return fmaf(2.0f, __builtin_amdgcn_rcpf(1.0f + exp2_hw(zs)), -1.0f);
}
__device__ __forceinline__ float tanh_fast(float z) {     // unscaled input (c-state)
    return fmaf(2.0f, __builtin_amdgcn_rcpf(1.0f + exp2_hw(-2.885390082f * z)), -1.0f);
}
__device__ __forceinline__ unsigned short f2bf(float f) {
    unsigned u = __float_as_uint(f);
    return (unsigned short)((u + 0x7fffu + ((u >> 16) & 1u)) >> 16);
}
__device__ __forceinline__ float bf2f(unsigned short s) {
    return __uint_as_float(((unsigned)s) << 16);
}
__device__ __forceinline__ void split8s(const float* __restrict__ p, float s,
                                        bf16x8& hi, bf16x8& lo) {
    float4 a = *(const float4*)p;
    float4 b = *(const float4*)(p + 4);
    float t[8] = {a.x * s, a.y * s, a.z * s, a.w * s, b.x * s, b.y * s, b.z * s, b.w * s};
    #pragma unroll
    for (int i = 0; i < 8; ++i) {
        unsigned short h = f2bf(t[i]);
        hi[i] = (short)h;
        lo[i] = (short)f2bf(t[i] - bf2f(h));
    }
}
// lane c <-> lane c^8 exchange (within 32-lane groups) on the DS pipe
__device__ __forceinline__ float xor8(float v) {
    return __int_as_float(__builtin_amdgcn_ds_swizzle(__float_as_int(v), 0x201F));
}

__global__ __launch_bounds__(NT, 1) void lstm2_fused_kernel(
    const float* __restrict__ x,
    const float* __restrict__ W_ih0, const float* __restrict__ W_hh0,
    const float* __restrict__ b_ih0, const float* __restrict__ b_hh0,
    const float* __restrict__ W_ih1, const float* __restrict__ W_hh1,
    const float* __restrict__ b_ih1, const float* __restrict__ b_hh1,
    const float* __restrict__ fc_W,  const float* __restrict__ fc_b,
    float* __restrict__ out)
{
    // frag buffers: cols 0-7 = h_hi(b0..7), cols 8-15 = h_lo(b0..7)
    __shared__ alignas(16) unsigned short h1buf[2][1024];    // 4 KB
    __shared__ alignas(16) unsigned short h2buf[2][1024];    // 4 KB
    __shared__ float x_lds2[TT][NB];                         // 16 KB, [t][b]
    __shared__ float fc_part[32][NB];

    const int tid  = threadIdx.x;
    const int lane = tid & 63;
    const int wloc = tid >> 6;          // 0..3: tile-set for BOTH layers
    const int lr = lane & 15;           // col: batch (0-7) or lo-correction (8-15)
    const int lg = lane >> 4;
    const int b0 = blockIdx.x * NB;
    const bool lo8 = (lr < 8);
    const int rb = lo8 ? 0 : 2;         // r-split: which 2 acc slots this lane activates

    // ---- stage x transposed; zero h buffers ----
    {
        const float4* xs = (const float4*)(x + (size_t)b0 * TT);
        #pragma unroll
        for (int i = 0; i < 4; ++i) {
            int idx = i * NT + tid;          // 0..1023 float4s
            float4 v = xs[idx];
            int b  = idx >> 7;
            int t4 = (idx & 127) << 2;
            x_lds2[t4 + 0][b] = v.x;
            x_lds2[t4 + 1][b] = v.y;
            x_lds2[t4 + 2][b] = v.z;
            x_lds2[t4 + 3][b] = v.w;
        }
        int* hz = (int*)h1buf;
        #pragma unroll
        for (int i = 0; i < 4; ++i) hz[i * NT + tid] = 0;
        int* h2z = (int*)h2buf;
        #pragma unroll
        for (int i = 0; i < 4; ++i) h2z[i * NT + tid] = 0;
    }

    // ---- per-wave static weights, both layers (pre-scaled by -log2e / -2log2e) ----
    bf16x8 A0hi[8], A0lo[8];      // L0: [j*2+kt]
    bf16x8 A1hi[16], A1lo[16];    // L1: [j*4+kt] (kt<2: W_ih1, kt>=2: W_hh1)
    float bias0[16], wxv0[16], bias1[16];
    float cst0 = 0.f, cst1 = 0.f;       // L0 c-state (this lane's 2 units)
    float dst0 = 0.f, dst1 = 0.f;       // L1 c-state
    const int base_u = 16 * wloc + 4 * lg;
    const int u0 = base_u + rb;
    const int wo  = ((lr & 7) + 16 * (base_u >> 3)) * 8 + (base_u & 7) + rb;
    const int fro = lane * 8;

    #pragma unroll
    for (int j = 0; j < 4; ++j) {
        const float sj = (j == 2) ? (-2.0f * L2E) : (-L2E);
        const int row = j * 64 + 16 * wloc + lr;
        #pragma unroll
        for (int kt = 0; kt < 2; ++kt)
            split8s(W_hh0 + row * H + kt * 32 + 8 * lg, sj, A0hi[j * 2 + kt], A0lo[j * 2 + kt]);
        #pragma unroll
        for (int kt = 0; kt < 4; ++kt) {
            const float* p = (kt < 2) ? (W_ih1 + row * H + kt * 32 + 8 * lg)
                                      : (W_hh1 + row * H + (kt - 2) * 32 + 8 * lg);
            split8s(p, sj, A1hi[j * 4 + kt], A1lo[j * 4 + kt]);
        }
        const int rowc = j * 64 + base_u;
        #pragma unroll
        for (int r = 0; r < 4; ++r) {
            bias0[j * 4 + r] = lo8 ? (b_ih0[rowc + r] + b_hh0[rowc + r]) * sj : 0.f;
            wxv0 [j * 4 + r] = lo8 ? W_ih0[rowc + r] * sj : 0.f;
            bias1[j * 4 + r] = lo8 ? (b_ih1[rowc + r] + b_hh1[rowc + r]) * sj : 0.f;
        }
    }
    #pragma unroll
    for (int i = 0; i < 8; ++i)  { asm volatile("" : "+v"(A0hi[i])); asm volatile("" : "+v"(A0lo[i])); }
    #pragma unroll
    for (int i = 0; i < 16; ++i) { asm volatile("" : "+v"(A1hi[i])); asm volatile("" : "+v"(A1lo[i])); }
    #pragma unroll
    for (int i = 0; i < 16; ++i) {
        asm volatile("" : "+v"(bias0[i])); asm volatile("" : "+v"(wxv0[i]));
        asm volatile("" : "+v"(bias1[i]));
    }

    __syncthreads();

    f32x4 acc0[4], acc1[4];

    auto l0_mfma = [&](int t) {
        const unsigned short* ph = &h1buf[(t - 1) & 1][0];
        bf16x8 Bh0 = *(const bf16x8*)(ph + fro);
        bf16x8 Bh1 = *(const bf16x8*)(ph + 512 + fro);
        const float xv = x_lds2[t][lane & 7];
        #pragma unroll
        for (int j = 0; j < 4; ++j)
            #pragma unroll
            for (int r = 0; r < 4; ++r)
                acc0[j][r] = fmaf(wxv0[j * 4 + r], xv, bias0[j * 4 + r]);
        #pragma unroll
        for (int j = 0; j < 4; ++j) {
            MFMA(A0hi[j * 2 + 0], Bh0, acc0[j]);
            MFMA(A0lo[j * 2 + 0], Bh0, acc0[j]);
            MFMA(A0hi[j * 2 + 1], Bh1, acc0[j]);
            MFMA(A0lo[j * 2 + 1], Bh1, acc0[j]);
        }
    };
    auto l1_mfma = [&](int t) {        // computes gates of h2(t-1)
        const unsigned short* p1 = &h1buf[(t - 1) & 1][0];
        const unsigned short* p2 = &h2buf[t & 1][0];
        bf16x8 B1[4];
        B1[0] = *(const bf16x8*)(p1 + fro);
        B1[1] = *(const bf16x8*)(p1 + 512 + fro);
        B1[2] = *(const bf16x8*)(p2 + fro);
        B1[3] = *(const bf16x8*)(p2 + 512 + fro);
        #pragma unroll
        for (int j = 0; j < 4; ++j)
            #pragma unroll
            for (int r = 0; r < 4; ++r)
                acc1[j][r] = bias1[j * 4 + r];
        #pragma unroll
        for (int j = 0; j < 4; ++j)
            #pragma unroll
            for (int kt = 0; kt < 4; ++kt) {
                MFMA(A1hi[j * 4 + kt], B1[kt], acc1[j]);
                MFMA(A1lo[j * 4 + kt], B1[kt], acc1[j]);
            }
    };
    // single-swizzle fold: each lane sends the slots its xor-8 partner needs
    auto fold = [&](f32x4* acc, float zs[4][2]) {
        #pragma unroll
        for (int j = 0; j < 4; ++j) {
            const float s0 = lo8 ? acc[j][2] : acc[j][0];
            const float s1 = lo8 ? acc[j][3] : acc[j][1];
            const float r0 = xor8(s0);
            const float r1 = xor8(s1);
            zs[j][0] = (lo8 ? acc[j][0] : acc[j][2]) + r0;
            zs[j][1] = (lo8 ? acc[j][1] : acc[j][3]) + r1;
        }
    };
    auto act = [&](float zs[4][2], float& cs0, float& cs1, float& hv0, float& hv1) {
        cs0 = fmaf(sigm_pre(zs[1][0]), cs0, sigm_pre(zs[0][0]) * tanh_pre(zs[2][0]));
        cs1 = fmaf(sigm_pre(zs[1][1]), cs1, sigm_pre(zs[0][1]) * tanh_pre(zs[2][1]));
        hv0 = sigm_pre(zs[3][0]) * tanh_fast(cs0);
        hv1 = sigm_pre(zs[3][1]) * tanh_fast(cs1);
    };
    auto pack_write = [&](unsigned short* buf, float hv0, float hv1) {
        unsigned p, q;
        asm("v_cvt_pk_bf16_f32 %0, %1, %2" : "=v"(p) : "v"(hv0), "v"(hv1));
        const float r0 = hv0 - __uint_as_float(p << 16);
        const float r1 = hv1 - __uint_as_float(p & 0xffff0000u);
        asm("v_cvt_pk_bf16_f32 %0, %1, %2" : "=v"(q) : "v"(r0), "v"(r1));
        *(unsigned*)&buf[wo]      = p;   // hi -> col c
        *(unsigned*)&buf[wo + 64] = q;   // lo -> col c+8
    };

    // ---- t = 0: L0 only (h1(-1), read from zeroed h1buf[1]) ----
    {
        l0_mfma(0);
        float zs[4][2]; fold(acc0, zs);
        float hv0, hv1; act(zs, cst0, cst1, hv0, hv1);
        pack_write(&h1buf[0][0], hv0, hv1);
    }
    __syncthreads();

    // ---- main loop: straight-line both-layer body, ONE barrier per step ----
    for (int t = 1; t < TT; ++t) {
        l1_mfma(t);          // issued first -> chains retire while L0 MFMAs queue
        l0_mfma(t);
        {   // L1 finish: h2(t-1) -> h2buf[(t-1)&1] == [(t+1)&1]
            float zs[4][2]; fold(acc1, zs);
            float hv0, hv1; act(zs, dst0, dst1, hv0, hv1);
            pack_write(&h2buf[(t + 1) & 1][0], hv0, hv1);
        }
        {   // L0 finish: h1(t) -> h1buf[t&1]
            float zs[4][2]; fold(acc0, zs);
            float hv0, hv1; act(zs, cst0, cst1, hv0, hv1);
            pack_write(&h1buf[t & 1][0], hv0, hv1);
        }
        __syncthreads();
    }

    // ---- t = TT: L1 only, then FC partials ----
    {
        l1_mfma(TT);
        float zs[4][2]; fold(acc1, zs);
        float hv0, hv1; act(zs, dst0, dst1, hv0, hv1);
        fc_part[wloc * 8 + lg * 2 + (lo8 ? 0 : 1)][lr & 7] =
            fc_W[u0] * hv0 + fc_W[u0 + 1] * hv1;
    }
    __syncthreads();

    // ---- final FC reduce (deterministic) ----
    if (tid < NB) {
        float s = fc_b[0];
        #pragma unroll
        for (int i = 0; i < 32; ++i) s += fc_part[i][tid];
        out[b0 + tid] = s;
    }
}

} // namespace

extern "C" void kernel_launch(void* const* d_in, const int* in_sizes, int n_in,
                              void* d_out, int out_size, void* d_ws, size_t ws_size,
                              hipStream_t stream)
{
    const float* x     = (const float*)d_in[0];
    const float* W_ih0 = (const float*)d_in[1];
    const float* W_hh0 = (const float*)d_in[2];
    const float* b_ih0 = (const float*)d_in[3];
    const float* b_hh0 = (const float*)d_in[4];
    const float* W_ih1 = (const float*)d_in[5];
    const float* W_hh1 = (const float*)d_in[6];
    const float* b_ih1 = (const float*)d_in[7];
    const float* b_hh1 = (const float*)d_in[8];
    const float* fc_W  = (const float*)d_in[9];
    const float* fc_b  = (const float*)d_in[10];
    float* out = (float*)d_out;

    const int B = in_sizes[0] / TT;          // 2048
    dim3 grid(B / NB), block(NT);            // 256 blocks x 256 threads, 1 block/CU
    hipLaunchKernelGGL(lstm2_fused_kernel, grid, block, 0, stream,
                       x, W_ih0, W_hh0, b_ih0, b_hh0,
                       W_ih1, W_hh1, b_ih1, b_hh1, fc_W, fc_b, out);
}

// Round 8
// 447.460 us; speedup vs baseline: 1.4299x; 1.4299x over previous
//
#include <hip/hip_runtime.h>

namespace {

constexpr int TT = 512;   // timesteps
constexpr int H  = 64;    // hidden units per layer
constexpr int NB = 8;     // real batches per block; MFMA cols 8..15 carry h_lo
constexpr int NT = 512;   // 8 waves: 0-3 -> layer0, 4-7 -> layer1
constexpr float L2E = 1.442695041f;

typedef float  f32x4  __attribute__((ext_vector_type(4)));
typedef short  bf16x8 __attribute__((ext_vector_type(8)));

#define MFMA(A, B, C) (C) = __builtin_amdgcn_mfma_f32_16x16x32_bf16((A), (B), (C), 0, 0, 0)

__device__ __forceinline__ float exp2_hw(float x) {
    float r; asm("v_exp_f32 %0, %1" : "=v"(r) : "v"(x)); return r;
}
__device__ __forceinline__ float sigm_pre(float zs) {     // zs = -log2e * z
    return __builtin_amdgcn_rcpf(1.0f + exp2_hw(zs));
}
__device__ __forceinline__ float tanh_pre(float zs) {     // zs = -2*log2e * z
    return fmaf(2.0f, __builtin_amdgcn_rcpf(1.0f + exp2_hw(zs)), -1.0f);
}
__device__ __forceinline__ float tanh_fast(float z) {     // unscaled input (c-state)
    return fmaf(2.0f, __builtin_amdgcn_rcpf(1.0f + exp2_hw(-2.885390082f * z)), -1.0f);
}
__device__ __forceinline__ unsigned short f2bf(float f) {
    unsigned u = __float_as_uint(f);
    return (unsigned short)((u + 0x7fffu + ((u >> 16) & 1u)) >> 16);
}
__device__ __forceinline__ float bf2f(unsigned short s) {
    return __uint_as_float(((unsigned)s) << 16);
}
// lane c <-> lane c^8 exchange (within 32-lane groups) on the DS pipe
__device__ __forceinline__ float xor8(float v) {
    return __int_as_float(__builtin_amdgcn_ds_swizzle(__float_as_int(v), 0x201F));
}

__device__ __forceinline__ void waitge(int* c, int v) {
    while (__hip_atomic_load(c, __ATOMIC_ACQUIRE, __HIP_MEMORY_SCOPE_WORKGROUP) < v) {}
}
// fast-path check, then sleep-backed poll (no issue-slot pollution)
__device__ __forceinline__ void waitge_sleep(int* c, int v) {
    if (__hip_atomic_load(c, __ATOMIC_ACQUIRE, __HIP_MEMORY_SCOPE_WORKGROUP) >= v) return;
    do { __builtin_amdgcn_s_sleep(1); }
    while (__hip_atomic_load(c, __ATOMIC_ACQUIRE, __HIP_MEMORY_SCOPE_WORKGROUP) < v);
}
__device__ __forceinline__ void signal(int* c) {
    if ((threadIdx.x & 63) == 0)
        (void)__hip_atomic_fetch_add(c, 1, __ATOMIC_RELEASE, __HIP_MEMORY_SCOPE_WORKGROUP);
}

// ws fragment layout (bf16x8 slots, 16B each):
//   L0:  slot = ((row*2 + kt)*2 + half)*4 + lg          rows 256, kt<2   (W_hh0)
//   L1:  slot = 4096 + ((row*4 + kt)*2 + half)*4 + lg   rows 256, kt<4   (W_ih1|W_hh1)
// total 12288 slots = 192 KB. Rows pre-scaled by -log2e (-2log2e for g-gate rows).

__global__ void prep_weights(const float* __restrict__ W_hh0,
                             const float* __restrict__ W_ih1,
                             const float* __restrict__ W_hh1,
                             unsigned short* __restrict__ ws)
{
    const int id = blockIdx.x * blockDim.x + threadIdx.x;   // 0..6143
    int row, kt, lg;
    const float* p;
    int base;
    if (id < 2048) {                 // L0: per row 2 kt x 4 lg
        row = id >> 3; kt = (id >> 2) & 1; lg = id & 3;
        p = W_hh0 + row * 64 + kt * 32 + lg * 8;
        base = ((row * 2 + kt) * 2) * 4 + lg;               // half=0 slot
    } else {                         // L1: per row 4 kt x 4 lg
        const int id2 = id - 2048;
        row = id2 >> 4; kt = (id2 >> 2) & 3; lg = id2 & 3;
        p = (kt < 2) ? (W_ih1 + row * 64 + kt * 32 + lg * 8)
                     : (W_hh1 + row * 64 + (kt - 2) * 32 + lg * 8);
        base = 4096 + ((row * 4 + kt) * 2) * 4 + lg;
    }
    const float sj = ((row >> 6) == 2) ? (-2.0f * L2E) : (-L2E);
    float4 a = *(const float4*)p;
    float4 b = *(const float4*)(p + 4);
    float t[8] = {a.x * sj, a.y * sj, a.z * sj, a.w * sj,
                  b.x * sj, b.y * sj, b.z * sj, b.w * sj};
    bf16x8 hi, lo;
    #pragma unroll
    for (int i = 0; i < 8; ++i) {
        unsigned short h = f2bf(t[i]);
        hi[i] = (short)h;
        lo[i] = (short)f2bf(t[i] - bf2f(h));
    }
    *(bf16x8*)(ws + (size_t)base * 8)       = hi;           // half=0
    *(bf16x8*)(ws + (size_t)(base + 4) * 8) = lo;           // half=1 (+4 slots)
}

__global__ __launch_bounds__(NT, 2) void lstm2_mfma_kernel(
    const float* __restrict__ x,
    const unsigned short* __restrict__ wfrag,
    const float* __restrict__ W_ih0,
    const float* __restrict__ b_ih0, const float* __restrict__ b_hh0,
    const float* __restrict__ b_ih1, const float* __restrict__ b_hh1,
    const float* __restrict__ fc_W,  const float* __restrict__ fc_b,
    float* __restrict__ out)
{
    // single frag buffer per slot: cols 0-7 = h_hi(b0..7), cols 8-15 = h_lo(b0..7)
    __shared__ alignas(16) unsigned short h1ring[4][1024];   // 8 KB
    __shared__ alignas(16) unsigned short h2buf[2][1024];    // 4 KB
    __shared__ float x_lds2[TT][NB];                         // 16 KB, [t][b]
    __shared__ float fc_part[32][NB];
    __shared__ int c0, c1c, c1d;

    const int tid  = threadIdx.x;
    const int lane = tid & 63;
    const int wid  = tid >> 6;          // 0..7
    const int wloc = wid & 3;
    const bool isL1 = wid >= 4;
    const int lr = lane & 15;           // col: batch (0-7) or lo-correction (8-15)
    const int lg = lane >> 4;
    const int b0 = blockIdx.x * NB;
    const bool lo8 = (lr < 8);
    const int rb = lo8 ? 0 : 2;         // r-split: which 2 acc slots this lane activates

    // ---- stage x transposed ----
    {
        const float4* xs = (const float4*)(x + (size_t)b0 * TT);
        #pragma unroll
        for (int i = 0; i < 2; ++i) {
            int idx = i * NT + tid;
            float4 v = xs[idx];
            int b  = idx >> 7;
            int t4 = (idx & 127) << 2;
            x_lds2[t4 + 0][b] = v.x;
            x_lds2[t4 + 1][b] = v.y;
            x_lds2[t4 + 2][b] = v.z;
            x_lds2[t4 + 3][b] = v.w;
        }
    }
    // ---- zero h buffers ----
    {
        int* hz = (int*)h1ring;
        #pragma unroll
        for (int i = 0; i < 4; ++i) hz[i * NT + tid] = 0;
        int* h2z = (int*)h2buf;
        #pragma unroll
        for (int i = 0; i < 2; ++i) h2z[i * NT + tid] = 0;
    }
    if (tid == 0) { c0 = 0; c1c = 0; c1d = 0; }

    // ---- per-wave static weights: pre-split fragments, plain 16B loads ----
    bf16x8 Ahi[16], Alo[16];
    float bias[16], wxv[16];
    float cst0 = 0.f, cst1 = 0.f;
    const int base_u = 16 * wloc + 4 * lg;
    const int u0 = base_u + rb;
    const int wo  = ((lr & 7) + 16 * (base_u >> 3)) * 8 + (base_u & 7) + rb;
    const int fro = lane * 8;

    if (!isL1) {
        #pragma unroll
        for (int j = 0; j < 4; ++j) {
            const int row = j * 64 + 16 * wloc + lr;
            #pragma unroll
            for (int kt = 0; kt < 2; ++kt) {
                const int s0 = ((row * 2 + kt) * 2) * 4 + lg;
                Ahi[j * 2 + kt] = *(const bf16x8*)(wfrag + (size_t)s0 * 8);
                Alo[j * 2 + kt] = *(const bf16x8*)(wfrag + (size_t)(s0 + 4) * 8);
            }
            const float sj = (j == 2) ? (-2.0f * L2E) : (-L2E);
            const int rowc = j * 64 + base_u;
            #pragma unroll
            for (int r = 0; r < 4; ++r) {
                bias[j * 4 + r] = lo8 ? (b_ih0[rowc + r] + b_hh0[rowc + r]) * sj : 0.f;
                wxv [j * 4 + r] = lo8 ? W_ih0[rowc + r] * sj : 0.f;
            }
        }
    } else {
        #pragma unroll
        for (int j = 0; j < 4; ++j) {
            const int row = j * 64 + 16 * wloc + lr;
            #pragma unroll
            for (int kt = 0; kt < 4; ++kt) {
                const int s0 = 4096 + ((row * 4 + kt) * 2) * 4 + lg;
                Ahi[j * 4 + kt] = *(const bf16x8*)(wfrag + (size_t)s0 * 8);
                Alo[j * 4 + kt] = *(const bf16x8*)(wfrag + (size_t)(s0 + 4) * 8);
            }
            const float sj = (j == 2) ? (-2.0f * L2E) : (-L2E);
            const int rowc = j * 64 + base_u;
            #pragma unroll
            for (int r = 0; r < 4; ++r)
                bias[j * 4 + r] = lo8 ? (b_ih1[rowc + r] + b_hh1[rowc + r]) * sj : 0.f;
        }
    }

    __syncthreads();

    if (!isL1) {
        // ============ L0: computes h1(t). Ring gate = L1's MFMA-end (c1c) ============
        for (int t = 0; t < TT; ++t) {
            waitge(&c0, 4 * t);                              // peers done t-1 (short)
            if (t >= 4) waitge_sleep(&c1c, 4 * (t - 3));     // ring slot t&3 consumed
            const unsigned short* ph = &h1ring[(t - 1) & 3][0];
            bf16x8 Bh0 = *(const bf16x8*)(ph + fro);
            bf16x8 Bh1 = *(const bf16x8*)(ph + 512 + fro);
            const float xv = x_lds2[t][lane & 7];
            f32x4 acc[4];
            #pragma unroll
            for (int j = 0; j < 4; ++j)
                #pragma unroll
                for (int r = 0; r < 4; ++r)
                    acc[j][r] = fmaf(wxv[j * 4 + r], xv, bias[j * 4 + r]);
            __builtin_amdgcn_s_setprio(1);
            #pragma unroll
            for (int j = 0; j < 4; ++j) {
                MFMA(Ahi[j * 2 + 0], Bh0, acc[j]);
                MFMA(Alo[j * 2 + 0], Bh0, acc[j]);
                MFMA(Ahi[j * 2 + 1], Bh1, acc[j]);
                MFMA(Alo[j * 2 + 1], Bh1, acc[j]);
            }
            __builtin_amdgcn_s_setprio(0);
            float zs[4][2];
            #pragma unroll
            for (int j = 0; j < 4; ++j) {
                const float s0 = lo8 ? acc[j][2] : acc[j][0];
                const float s1 = lo8 ? acc[j][3] : acc[j][1];
                const float r0 = xor8(s0);
                const float r1 = xor8(s1);
                zs[j][0] = (lo8 ? acc[j][0] : acc[j][2]) + r0;
                zs[j][1] = (lo8 ? acc[j][1] : acc[j][3]) + r1;
            }
            cst0 = fmaf(sigm_pre(zs[1][0]), cst0, sigm_pre(zs[0][0]) * tanh_pre(zs[2][0]));
            cst1 = fmaf(sigm_pre(zs[1][1]), cst1, sigm_pre(zs[0][1]) * tanh_pre(zs[2][1]));
            const float hv0 = sigm_pre(zs[3][0]) * tanh_fast(cst0);
            const float hv1 = sigm_pre(zs[3][1]) * tanh_fast(cst1);
            unsigned p, q;
            asm("v_cvt_pk_bf16_f32 %0, %1, %2" : "=v"(p) : "v"(hv0), "v"(hv1));
            const float r0 = hv0 - __uint_as_float(p << 16);
            const float r1 = hv1 - __uint_as_float(p & 0xffff0000u);
            asm("v_cvt_pk_bf16_f32 %0, %1, %2" : "=v"(q) : "v"(r0), "v"(r1));
            *(unsigned*)&h1ring[t & 3][wo]      = p;    // hi -> col c
            *(unsigned*)&h1ring[t & 3][wo + 64] = q;    // lo -> col c+8
            signal(&c0);
        }
    } else {
        // ============ L1: iter t computes h2(t-1) ============
        for (int t = 1; t <= TT; ++t) {
            waitge_sleep(&c1d, 4 * (t - 1));          // peers' h2(t-2) written
            waitge_sleep(&c0, 4 * t);                 // h1(t-1) ready (rarely binds)
            const unsigned short* p1 = &h1ring[(t - 1) & 3][0];
            const unsigned short* p2 = &h2buf[(t - 2) & 1][0];
            bf16x8 Bh[4];
            Bh[0] = *(const bf16x8*)(p1 + fro);
            Bh[1] = *(const bf16x8*)(p1 + 512 + fro);
            Bh[2] = *(const bf16x8*)(p2 + fro);
            Bh[3] = *(const bf16x8*)(p2 + 512 + fro);
            f32x4 acc[4];
            #pragma unroll
            for (int j = 0; j < 4; ++j)
                #pragma unroll
                for (int r = 0; r < 4; ++r)
                    acc[j][r] = bias[j * 4 + r];
            __builtin_amdgcn_s_setprio(1);
            #pragma unroll
            for (int j = 0; j < 4; ++j)
                #pragma unroll
                for (int kt = 0; kt < 4; ++kt) {
                    MFMA(Ahi[j * 4 + kt], Bh[kt], acc[j]);
                    MFMA(Alo[j * 4 + kt], Bh[kt], acc[j]);
                }
            __builtin_amdgcn_s_setprio(0);
            // early ring-consume signal: releases L0 at our MFMA-end -> anti-phase
            __builtin_amdgcn_sched_barrier(0);
            signal(&c1c);
            float zs[4][2];
            #pragma unroll
            for (int j = 0; j < 4; ++j) {
                const float s0 = lo8 ? acc[j][2] : acc[j][0];
                const float s1 = lo8 ? acc[j][3] : acc[j][1];
                const float r0 = xor8(s0);
                const float r1 = xor8(s1);
                zs[j][0] = (lo8 ? acc[j][0] : acc[j][2]) + r0;
                zs[j][1] = (lo8 ? acc[j][1] : acc[j][3]) + r1;
            }
            cst0 = fmaf(sigm_pre(zs[1][0]), cst0, sigm_pre(zs[0][0]) * tanh_pre(zs[2][0]));
            cst1 = fmaf(sigm_pre(zs[1][1]), cst1, sigm_pre(zs[0][1]) * tanh_pre(zs[2][1]));
            const float hv0 = sigm_pre(zs[3][0]) * tanh_fast(cst0);
            const float hv1 = sigm_pre(zs[3][1]) * tanh_fast(cst1);
            unsigned p, q;
            asm("v_cvt_pk_bf16_f32 %0, %1, %2" : "=v"(p) : "v"(hv0), "v"(hv1));
            const float r0 = hv0 - __uint_as_float(p << 16);
            const float r1 = hv1 - __uint_as_float(p & 0xffff0000u);
            asm("v_cvt_pk_bf16_f32 %0, %1, %2" : "=v"(q) : "v"(r0), "v"(r1));
            *(unsigned*)&h2buf[(t - 1) & 1][wo]      = p;
            *(unsigned*)&h2buf[(t - 1) & 1][wo + 64] = q;
            if (t == TT) {
                const float s = fc_W[u0] * hv0 + fc_W[u0 + 1] * hv1;
                fc_part[(wid - 4) * 8 + lg * 2 + (lo8 ? 0 : 1)][lr & 7] = s;
            }
            signal(&c1d);
        }
    }

    __syncthreads();

    // ---- final FC reduce (deterministic) ----
    if (tid < NB) {
        float s = fc_b[0];
        #pragma unroll
        for (int i = 0; i < 32; ++i) s += fc_part[i][tid];
        out[b0 + tid] = s;
    }
}

} // namespace

extern "C" void kernel_launch(void* const* d_in, const int* in_sizes, int n_in,
                              void* d_out, int out_size, void* d_ws, size_t ws_size,
                              hipStream_t stream)
{
    const float* x     = (const float*)d_in[0];
    const float* W_ih0 = (const float*)d_in[1];
    const float* W_hh0 = (const float*)d_in[2];
    const float* b_ih0 = (const float*)d_in[3];
    const float* b_hh0 = (const float*)d_in[4];
    const float* W_ih1 = (const float*)d_in[5];
    const float* W_hh1 = (const float*)d_in[6];
    const float* b_ih1 = (const float*)d_in[7];
    const float* b_hh1 = (const float*)d_in[8];
    const float* fc_W  = (const float*)d_in[9];
    const float* fc_b  = (const float*)d_in[10];
    float* out = (float*)d_out;
    unsigned short* ws = (unsigned short*)d_ws;    // 192 KB of pre-split fragments

    // 1) pre-split weight fragments into d_ws (scale folded, hi/lo bf16)
    hipLaunchKernelGGL(prep_weights, dim3(24), dim3(256), 0, stream,
                       W_hh0, W_ih1, W_hh1, ws);

    // 2) main recurrent kernel
    const int B = in_sizes[0] / TT;          // 2048
    dim3 grid(B / NB), block(NT);            // 256 blocks x 512 threads
    hipLaunchKernelGGL(lstm2_mfma_kernel, grid, block, 0, stream,
                       x, ws, W_ih0, b_ih0, b_hh0, b_ih1, b_hh1, fc_W, fc_b, out);
}

// Round 9
// 424.149 us; speedup vs baseline: 1.5085x; 1.0550x over previous
//
#include <hip/hip_runtime.h>

namespace {

constexpr int TT = 512;   // timesteps
constexpr int H  = 64;    // hidden units per layer
constexpr int NB = 8;     // real batches per block; MFMA cols 8..15 carry h_lo
constexpr int NT = 512;   // 8 waves: 0-3 -> layer0, 4-7 -> layer1
constexpr float L2E = 1.442695041f;

typedef float  f32x4  __attribute__((ext_vector_type(4)));
typedef short  bf16x8 __attribute__((ext_vector_type(8)));

#define MFMA(A, B, C) (C) = __builtin_amdgcn_mfma_f32_16x16x32_bf16((A), (B), (C), 0, 0, 0)

__device__ __forceinline__ float exp2_hw(float x) {
    float r; asm("v_exp_f32 %0, %1" : "=v"(r) : "v"(x)); return r;
}
__device__ __forceinline__ float sigm_pre(float zs) {     // zs = -log2e * z
    return __builtin_amdgcn_rcpf(1.0f + exp2_hw(zs));
}
__device__ __forceinline__ float tanh_pre(float zs) {     // zs = -2*log2e * z
    return fmaf(2.0f, __builtin_amdgcn_rcpf(1.0f + exp2_hw(zs)), -1.0f);
}
__device__ __forceinline__ float tanh_fast(float z) {     // unscaled input (c-state)
    return fmaf(2.0f, __builtin_amdgcn_rcpf(1.0f + exp2_hw(-2.885390082f * z)), -1.0f);
}
__device__ __forceinline__ unsigned short f2bf(float f) {
    unsigned u = __float_as_uint(f);
    return (unsigned short)((u + 0x7fffu + ((u >> 16) & 1u)) >> 16);
}
__device__ __forceinline__ float bf2f(unsigned short s) {
    return __uint_as_float(((unsigned)s) << 16);
}
// lane c <-> lane c^8 exchange (within 32-lane groups) on the DS pipe
__device__ __forceinline__ float xor8(float v) {
    return __int_as_float(__builtin_amdgcn_ds_swizzle(__float_as_int(v), 0x201F));
}

// busy poll only: sleep granularity (64 cyc) hurts critical-path detects
__device__ __forceinline__ void waitge(int* c, int v) {
    while (__hip_atomic_load(c, __ATOMIC_ACQUIRE, __HIP_MEMORY_SCOPE_WORKGROUP) < v) {}
}
__device__ __forceinline__ void signal(int* c) {
    if ((threadIdx.x & 63) == 0)
        (void)__hip_atomic_fetch_add(c, 1, __ATOMIC_RELEASE, __HIP_MEMORY_SCOPE_WORKGROUP);
}

// ws fragment layout (bf16x8 slots, 16B each):
//   L0:  slot = ((row*2 + kt)*2 + half)*4 + lg          rows 256, kt<2   (W_hh0)
//   L1:  slot = 4096 + ((row*4 + kt)*2 + half)*4 + lg   rows 256, kt<4   (W_ih1|W_hh1)
// Rows pre-scaled by -log2e (-2log2e for g-gate rows).

__global__ void prep_weights(const float* __restrict__ W_hh0,
                             const float* __restrict__ W_ih1,
                             const float* __restrict__ W_hh1,
                             unsigned short* __restrict__ ws)
{
    const int id = blockIdx.x * blockDim.x + threadIdx.x;   // 0..6143
    int row, kt, lg;
    const float* p;
    int base;
    if (id < 2048) {                 // L0: per row 2 kt x 4 lg
        row = id >> 3; kt = (id >> 2) & 1; lg = id & 3;
        p = W_hh0 + row * 64 + kt * 32 + lg * 8;
        base = ((row * 2 + kt) * 2) * 4 + lg;               // half=0 slot
    } else {                         // L1: per row 4 kt x 4 lg
        const int id2 = id - 2048;
        row = id2 >> 4; kt = (id2 >> 2) & 3; lg = id2 & 3;
        p = (kt < 2) ? (W_ih1 + row * 64 + kt * 32 + lg * 8)
                     : (W_hh1 + row * 64 + (kt - 2) * 32 + lg * 8);
        base = 4096 + ((row * 4 + kt) * 2) * 4 + lg;
    }
    const float sj = ((row >> 6) == 2) ? (-2.0f * L2E) : (-L2E);
    float4 a = *(const float4*)p;
    float4 b = *(const float4*)(p + 4);
    float t[8] = {a.x * sj, a.y * sj, a.z * sj, a.w * sj,
                  b.x * sj, b.y * sj, b.z * sj, b.w * sj};
    bf16x8 hi, lo;
    #pragma unroll
    for (int i = 0; i < 8; ++i) {
        unsigned short h = f2bf(t[i]);
        hi[i] = (short)h;
        lo[i] = (short)f2bf(t[i] - bf2f(h));
    }
    *(bf16x8*)(ws + (size_t)base * 8)       = hi;           // half=0
    *(bf16x8*)(ws + (size_t)(base + 4) * 8) = lo;           // half=1 (+4 slots)
}

__global__ __launch_bounds__(NT, 1) void lstm2_mfma_kernel(
    const float* __restrict__ x,
    const unsigned short* __restrict__ wfrag,
    const float* __restrict__ W_ih0,
    const float* __restrict__ b_ih0, const float* __restrict__ b_hh0,
    const float* __restrict__ b_ih1, const float* __restrict__ b_hh1,
    const float* __restrict__ fc_W,  const float* __restrict__ fc_b,
    float* __restrict__ out)
{
    // single frag buffer per slot: cols 0-7 = h_hi(b0..7), cols 8-15 = h_lo(b0..7)
    __shared__ alignas(16) unsigned short h1ring[4][1024];   // 8 KB
    __shared__ alignas(16) unsigned short h2buf[2][1024];    // 4 KB
    __shared__ float x_lds2[TT][NB];                         // 16 KB, [t][b]
    __shared__ float fc_part[32][NB];
    __shared__ int c0, c1c, c1d;

    const int tid  = threadIdx.x;
    const int lane = tid & 63;
    const int wid  = tid >> 6;          // 0..7
    const int wloc = wid & 3;
    const bool isL1 = wid >= 4;
    const int lr = lane & 15;           // col: batch (0-7) or lo-correction (8-15)
    const int lg = lane >> 4;
    const int b0 = blockIdx.x * NB;
    const bool lo8 = (lr < 8);
    const int rb = lo8 ? 0 : 2;         // r-split: which 2 acc slots this lane activates

    // ---- stage x transposed ----
    {
        const float4* xs = (const float4*)(x + (size_t)b0 * TT);
        #pragma unroll
        for (int i = 0; i < 2; ++i) {
            int idx = i * NT + tid;
            float4 v = xs[idx];
            int b  = idx >> 7;
            int t4 = (idx & 127) << 2;
            x_lds2[t4 + 0][b] = v.x;
            x_lds2[t4 + 1][b] = v.y;
            x_lds2[t4 + 2][b] = v.z;
            x_lds2[t4 + 3][b] = v.w;
        }
    }
    // ---- zero h buffers ----
    {
        int* hz = (int*)h1ring;
        #pragma unroll
        for (int i = 0; i < 4; ++i) hz[i * NT + tid] = 0;
        int* h2z = (int*)h2buf;
        #pragma unroll
        for (int i = 0; i < 2; ++i) h2z[i * NT + tid] = 0;
    }
    if (tid == 0) { c0 = 0; c1c = 0; c1d = 0; }

    // ---- per-wave static weights: pre-split fragments, plain 16B loads ----
    bf16x8 Ahi[16], Alo[16];
    float bias[16], wxv[16];
    float cst0 = 0.f, cst1 = 0.f;
    const int base_u = 16 * wloc + 4 * lg;
    const int u0 = base_u + rb;
    const int wo  = ((lr & 7) + 16 * (base_u >> 3)) * 8 + (base_u & 7) + rb;
    const int fro = lane * 8;

    if (!isL1) {
        #pragma unroll
        for (int j = 0; j < 4; ++j) {
            const int row = j * 64 + 16 * wloc + lr;
            #pragma unroll
            for (int kt = 0; kt < 2; ++kt) {
                const int s0 = ((row * 2 + kt) * 2) * 4 + lg;
                Ahi[j * 2 + kt] = *(const bf16x8*)(wfrag + (size_t)s0 * 8);
                Alo[j * 2 + kt] = *(const bf16x8*)(wfrag + (size_t)(s0 + 4) * 8);
            }
            const float sj = (j == 2) ? (-2.0f * L2E) : (-L2E);
            const int rowc = j * 64 + base_u;
            #pragma unroll
            for (int r = 0; r < 4; ++r) {
                bias[j * 4 + r] = lo8 ? (b_ih0[rowc + r] + b_hh0[rowc + r]) * sj : 0.f;
                wxv [j * 4 + r] = lo8 ? W_ih0[rowc + r] * sj : 0.f;
            }
        }
    } else {
        #pragma unroll
        for (int j = 0; j < 4; ++j) {
            const int row = j * 64 + 16 * wloc + lr;
            #pragma unroll
            for (int kt = 0; kt < 4; ++kt) {
                const int s0 = 4096 + ((row * 4 + kt) * 2) * 4 + lg;
                Ahi[j * 4 + kt] = *(const bf16x8*)(wfrag + (size_t)s0 * 8);
                Alo[j * 4 + kt] = *(const bf16x8*)(wfrag + (size_t)(s0 + 4) * 8);
            }
            const float sj = (j == 2) ? (-2.0f * L2E) : (-L2E);
            const int rowc = j * 64 + base_u;
            #pragma unroll
            for (int r = 0; r < 4; ++r)
                bias[j * 4 + r] = lo8 ? (b_ih1[rowc + r] + b_hh1[rowc + r]) * sj : 0.f;
        }
    }

    __syncthreads();

    if (!isL1) {
        // ============ L0: computes h1(t). Chain: peers' h1(t-1) -> h1(t) ============
        for (int t = 0; t < TT; ++t) {
            // off-critical init BEFORE the waits
            const float xv = x_lds2[t][lane & 7];
            f32x4 acc[4];
            #pragma unroll
            for (int j = 0; j < 4; ++j)
                #pragma unroll
                for (int r = 0; r < 4; ++r)
                    acc[j][r] = fmaf(wxv[j * 4 + r], xv, bias[j * 4 + r]);
            if (t >= 4) waitge(&c1c, 4 * (t - 3));     // ring slot t&3 consumed by L1
            waitge(&c0, 4 * t);                        // peers wrote h1(t-1)
            const unsigned short* ph = &h1ring[(t - 1) & 3][0];
            bf16x8 Bh0 = *(const bf16x8*)(ph + fro);
            bf16x8 Bh1 = *(const bf16x8*)(ph + 512 + fro);
            __builtin_amdgcn_s_setprio(1);
            #pragma unroll
            for (int j = 0; j < 4; ++j) {
                MFMA(Ahi[j * 2 + 0], Bh0, acc[j]);
                MFMA(Alo[j * 2 + 0], Bh0, acc[j]);
                MFMA(Ahi[j * 2 + 1], Bh1, acc[j]);
                MFMA(Alo[j * 2 + 1], Bh1, acc[j]);
            }
            __builtin_amdgcn_s_setprio(0);
            float zs[4][2];
            #pragma unroll
            for (int j = 0; j < 4; ++j) {
                const float s0 = lo8 ? acc[j][2] : acc[j][0];
                const float s1 = lo8 ? acc[j][3] : acc[j][1];
                const float r0 = xor8(s0);
                const float r1 = xor8(s1);
                zs[j][0] = (lo8 ? acc[j][0] : acc[j][2]) + r0;
                zs[j][1] = (lo8 ? acc[j][1] : acc[j][3]) + r1;
            }
            cst0 = fmaf(sigm_pre(zs[1][0]), cst0, sigm_pre(zs[0][0]) * tanh_pre(zs[2][0]));
            cst1 = fmaf(sigm_pre(zs[1][1]), cst1, sigm_pre(zs[0][1]) * tanh_pre(zs[2][1]));
            const float hv0 = sigm_pre(zs[3][0]) * tanh_fast(cst0);
            const float hv1 = sigm_pre(zs[3][1]) * tanh_fast(cst1);
            unsigned p, q;
            asm("v_cvt_pk_bf16_f32 %0, %1, %2" : "=v"(p) : "v"(hv0), "v"(hv1));
            const float r0 = hv0 - __uint_as_float(p << 16);
            const float r1 = hv1 - __uint_as_float(p & 0xffff0000u);
            asm("v_cvt_pk_bf16_f32 %0, %1, %2" : "=v"(q) : "v"(r0), "v"(r1));
            *(unsigned*)&h1ring[t & 3][wo]      = p;    // hi -> col c
            *(unsigned*)&h1ring[t & 3][wo + 64] = q;    // lo -> col c+8
            signal(&c0);
        }
    } else {
        // ============ L1 (software-pipelined): iter t computes h2(t-1) ============
        // kt0/1 (h1 part) runs OFF the h2 critical path, prefetched at prev iter end.
        f32x4 acc[4];
        bf16x8 B0, B1;
        // prologue: prefetch h1(0), init, kt01
        waitge(&c0, 4);
        {
            const unsigned short* p1 = &h1ring[0][0];
            B0 = *(const bf16x8*)(p1 + fro);
            B1 = *(const bf16x8*)(p1 + 512 + fro);
        }
        signal(&c1c);                         // consumed h1(0)
        #pragma unroll
        for (int j = 0; j < 4; ++j)
            #pragma unroll
            for (int r = 0; r < 4; ++r)
                acc[j][r] = bias[j * 4 + r];
        #pragma unroll
        for (int j = 0; j < 4; ++j) {
            MFMA(Ahi[j * 4 + 0], B0, acc[j]);
            MFMA(Alo[j * 4 + 0], B0, acc[j]);
            MFMA(Ahi[j * 4 + 1], B1, acc[j]);
            MFMA(Alo[j * 4 + 1], B1, acc[j]);
        }

        for (int t = 1; t <= TT; ++t) {
            // ---- critical section: h2(t-2) -> h2(t-1) ----
            waitge(&c1d, 4 * (t - 1));                // peers wrote h2(t-2)
            const unsigned short* p2 = &h2buf[(t - 2) & 1][0];
            bf16x8 B2 = *(const bf16x8*)(p2 + fro);
            bf16x8 B3 = *(const bf16x8*)(p2 + 512 + fro);
            __builtin_amdgcn_s_setprio(1);
            #pragma unroll
            for (int j = 0; j < 4; ++j) {
                MFMA(Ahi[j * 4 + 2], B2, acc[j]);
                MFMA(Alo[j * 4 + 2], B2, acc[j]);
                MFMA(Ahi[j * 4 + 3], B3, acc[j]);
                MFMA(Alo[j * 4 + 3], B3, acc[j]);
            }
            __builtin_amdgcn_s_setprio(0);
            float zs[4][2];
            #pragma unroll
            for (int j = 0; j < 4; ++j) {
                const float s0 = lo8 ? acc[j][2] : acc[j][0];
                const float s1 = lo8 ? acc[j][3] : acc[j][1];
                const float r0 = xor8(s0);
                const float r1 = xor8(s1);
                zs[j][0] = (lo8 ? acc[j][0] : acc[j][2]) + r0;
                zs[j][1] = (lo8 ? acc[j][1] : acc[j][3]) + r1;
            }
            cst0 = fmaf(sigm_pre(zs[1][0]), cst0, sigm_pre(zs[0][0]) * tanh_pre(zs[2][0]));
            cst1 = fmaf(sigm_pre(zs[1][1]), cst1, sigm_pre(zs[0][1]) * tanh_pre(zs[2][1]));
            const float hv0 = sigm_pre(zs[3][0]) * tanh_fast(cst0);
            const float hv1 = sigm_pre(zs[3][1]) * tanh_fast(cst1);
            unsigned p, q;
            asm("v_cvt_pk_bf16_f32 %0, %1, %2" : "=v"(p) : "v"(hv0), "v"(hv1));
            const float r0 = hv0 - __uint_as_float(p << 16);
            const float r1 = hv1 - __uint_as_float(p & 0xffff0000u);
            asm("v_cvt_pk_bf16_f32 %0, %1, %2" : "=v"(q) : "v"(r0), "v"(r1));
            *(unsigned*)&h2buf[(t - 1) & 1][wo]      = p;
            *(unsigned*)&h2buf[(t - 1) & 1][wo + 64] = q;
            signal(&c1d);
            // ---- off-critical: prefetch h1(t) and run kt01 for iter t+1 ----
            if (t < TT) {
                waitge(&c0, 4 * (t + 1));             // L0 ~4 ahead: fast path
                const unsigned short* p1 = &h1ring[t & 3][0];
                B0 = *(const bf16x8*)(p1 + fro);
                B1 = *(const bf16x8*)(p1 + 512 + fro);
                signal(&c1c);                         // consumed h1(t)
                #pragma unroll
                for (int j = 0; j < 4; ++j)
                    #pragma unroll
                    for (int r = 0; r < 4; ++r)
                        acc[j][r] = bias[j * 4 + r];
                #pragma unroll
                for (int j = 0; j < 4; ++j) {
                    MFMA(Ahi[j * 4 + 0], B0, acc[j]);
                    MFMA(Alo[j * 4 + 0], B0, acc[j]);
                    MFMA(Ahi[j * 4 + 1], B1, acc[j]);
                    MFMA(Alo[j * 4 + 1], B1, acc[j]);
                }
            } else {
                const float s = fc_W[u0] * hv0 + fc_W[u0 + 1] * hv1;
                fc_part[(wid - 4) * 8 + lg * 2 + (lo8 ? 0 : 1)][lr & 7] = s;
            }
        }
    }

    __syncthreads();

    // ---- final FC reduce (deterministic) ----
    if (tid < NB) {
        float s = fc_b[0];
        #pragma unroll
        for (int i = 0; i < 32; ++i) s += fc_part[i][tid];
        out[b0 + tid] = s;
    }
}

} // namespace

extern "C" void kernel_launch(void* const* d_in, const int* in_sizes, int n_in,
                              void* d_out, int out_size, void* d_ws, size_t ws_size,
                              hipStream_t stream)
{
    const float* x     = (const float*)d_in[0];
    const float* W_ih0 = (const float*)d_in[1];
    const float* W_hh0 = (const float*)d_in[2];
    const float* b_ih0 = (const float*)d_in[3];
    const float* b_hh0 = (const float*)d_in[4];
    const float* W_ih1 = (const float*)d_in[5];
    const float* W_hh1 = (const float*)d_in[6];
    const float* b_ih1 = (const float*)d_in[7];
    const float* b_hh1 = (const float*)d_in[8];
    const float* fc_W  = (const float*)d_in[9];
    const float* fc_b  = (const float*)d_in[10];
    float* out = (float*)d_out;
    unsigned short* ws = (unsigned short*)d_ws;    // 192 KB of pre-split fragments

    // 1) pre-split weight fragments into d_ws (scale folded, hi/lo bf16)
    hipLaunchKernelGGL(prep_weights, dim3(24), dim3(256), 0, stream,
                       W_hh0, W_ih1, W_hh1, ws);

    // 2) main recurrent kernel
    const int B = in_sizes[0] / TT;          // 2048
    dim3 grid(B / NB), block(NT);            // 256 blocks x 512 threads
    hipLaunchKernelGGL(lstm2_mfma_kernel, grid, block, 0, stream,
                       x, ws, W_ih0, b_ih0, b_hh0, b_ih1, b_hh1, fc_W, fc_b, out);
}